// Round 1
// baseline (1241.980 us; speedup 1.0000x reference)
//
#include <hip/hip_runtime.h>
#include <math.h>

#define BB 4
#define SS 1024
#define EE 1024
#define HH 16
#define DD 64
#define RR 129   // 2*MAX_REL+1

// ---------------------------------------------------------------------------
// Generic tiled fp32 GEMM: Y = X[M=4096,K=1024] @ W[K=1024,N=1024] + bias.
// to_heads=1: write Y in [B,H,S,D] layout (split heads). else plain [M,N].
// 64x64 tile, BK=16, 256 threads, 4x4 per thread. +1 LDS pad (<=2-way, free).
// ---------------------------------------------------------------------------
__global__ __launch_bounds__(256)
void gemm_bias_kernel(const float* __restrict__ X, const float* __restrict__ W,
                      const float* __restrict__ bias, float* __restrict__ Y,
                      const int to_heads)
{
    __shared__ float As[16][65];   // As[k][m]
    __shared__ float Bs[16][65];   // Bs[k][n]
    const int tid = threadIdx.x;
    const int tx = tid & 15, ty = tid >> 4;
    const int m0 = blockIdx.x * 64;
    const int n0 = blockIdx.y * 64;
    float acc[4][4] = {{0.f}};
    for (int k0 = 0; k0 < EE; k0 += 16) {
#pragma unroll
        for (int t = 0; t < 4; ++t) {
            const int idx = tid + t * 256;
            const int ra = idx >> 4, ca = idx & 15;       // A: 64 rows x 16 k
            As[ca][ra] = X[(size_t)(m0 + ra) * EE + k0 + ca];
            const int rb = idx >> 6, cb = idx & 63;       // B: 16 k x 64 cols
            Bs[rb][cb] = W[(size_t)(k0 + rb) * EE + n0 + cb];
        }
        __syncthreads();
#pragma unroll
        for (int kk = 0; kk < 16; ++kk) {
            float a[4], b[4];
#pragma unroll
            for (int i = 0; i < 4; ++i) a[i] = As[kk][ty * 4 + i];
#pragma unroll
            for (int j = 0; j < 4; ++j) b[j] = Bs[kk][tx * 4 + j];
#pragma unroll
            for (int i = 0; i < 4; ++i)
#pragma unroll
                for (int j = 0; j < 4; ++j)
                    acc[i][j] = fmaf(a[i], b[j], acc[i][j]);
        }
        __syncthreads();
    }
    const int h = n0 >> 6;   // BN=64 == D, so head is constant per block
#pragma unroll
    for (int i = 0; i < 4; ++i) {
        const int m = m0 + ty * 4 + i;
        float4 o;
        o.x = acc[i][0] + bias[n0 + tx * 4 + 0];
        o.y = acc[i][1] + bias[n0 + tx * 4 + 1];
        o.z = acc[i][2] + bias[n0 + tx * 4 + 2];
        o.w = acc[i][3] + bias[n0 + tx * 4 + 3];
        if (to_heads) {
            const int b_ = m >> 10, s = m & 1023;
            *(float4*)(Y + (((size_t)(b_ * HH + h)) * SS + s) * DD + tx * 4) = o;
        } else {
            *(float4*)(Y + (size_t)m * EE + n0 + tx * 4) = o;
        }
    }
}

// ---------------------------------------------------------------------------
// p_rel[m, r] = q_heads[m, :64] . emb[r, :64]    (m = bh*1024 + s, r in [0,129))
// One block = 64 rows. emb (129x64) + 64 q rows staged in LDS.
// ---------------------------------------------------------------------------
__global__ __launch_bounds__(256)
void relproj_kernel(const float* __restrict__ qh, const float* __restrict__ emb,
                    float* __restrict__ prel)
{
    __shared__ float semb[RR][65];
    __shared__ float sq[64][65];
    const int tid = threadIdx.x;
    const int row0 = blockIdx.x * 64;
    for (int i = tid; i < RR * DD; i += 256) semb[i / DD][i % DD] = emb[i];
    for (int i = tid; i < 64 * DD; i += 256) sq[i / DD][i % DD] = qh[(size_t)row0 * DD + i];
    __syncthreads();
    for (int idx = tid; idx < 64 * RR; idx += 256) {
        const int r = idx % RR;
        const int row = idx / RR;
        float acc = 0.f;
#pragma unroll
        for (int d = 0; d < DD; ++d) acc = fmaf(sq[row][d], semb[r][d], acc);
        prel[(size_t)(row0 + row) * RR + r] = acc;
    }
}

// ---------------------------------------------------------------------------
// scores[bh,i,j] = (q[bh,i,:].k[bh,j,:])/8 + p_rel[bh,i, clip(i-j)+64], masked.
// Written (pre-softmax) into d_out's attn region (used as scratch).
// 64x64 output tile per block, K=64 fully in LDS.
// ---------------------------------------------------------------------------
__global__ __launch_bounds__(256)
void scores_kernel(const float* __restrict__ qh, const float* __restrict__ kh,
                   const float* __restrict__ prel, const int* __restrict__ mask,
                   float* __restrict__ attn)
{
    __shared__ float Qs[64][65];
    __shared__ float Ks[64][65];
    const int tid = threadIdx.x;
    const int tx = tid & 15, ty = tid >> 4;
    const int j0 = blockIdx.x * 64;
    const int i0 = blockIdx.y * 64;
    const int bh = blockIdx.z;
    const int b_ = bh >> 4;
    const float* q = qh + (size_t)bh * SS * DD;
    const float* k = kh + (size_t)bh * SS * DD;
#pragma unroll
    for (int t = 0; t < 16; ++t) {
        const int idx = tid + t * 256;
        const int r = idx >> 6, c = idx & 63;
        Qs[r][c] = q[(size_t)(i0 + r) * DD + c];
        Ks[r][c] = k[(size_t)(j0 + r) * DD + c];
    }
    __syncthreads();
    float acc[4][4] = {{0.f}};
#pragma unroll 16
    for (int kk = 0; kk < DD; ++kk) {
        float a[4], b[4];
#pragma unroll
        for (int i = 0; i < 4; ++i) a[i] = Qs[ty * 4 + i][kk];
#pragma unroll
        for (int j = 0; j < 4; ++j) b[j] = Ks[tx * 4 + j][kk];
#pragma unroll
        for (int i = 0; i < 4; ++i)
#pragma unroll
            for (int j = 0; j < 4; ++j)
                acc[i][j] = fmaf(a[i], b[j], acc[i][j]);
    }
#pragma unroll
    for (int i = 0; i < 4; ++i) {
        const int gi = i0 + ty * 4 + i;
        const float* prow = prel + ((size_t)bh * SS + gi) * RR;
        const int* mrow = mask + ((size_t)b_ * SS + gi) * SS;
        float tmpv[4];
#pragma unroll
        for (int j = 0; j < 4; ++j) {
            const int gj = j0 + tx * 4 + j;
            int delta = gi - gj;
            delta = delta < -64 ? -64 : (delta > 64 ? 64 : delta);
            float sc = acc[i][j] * 0.125f + prow[delta + 64];
            if (mrow[gj] == 0) sc = -INFINITY;
            tmpv[j] = sc;
        }
        float4 o = {tmpv[0], tmpv[1], tmpv[2], tmpv[3]};
        *(float4*)(attn + ((size_t)bh * SS + gi) * SS + j0 + tx * 4) = o;
    }
}

// ---------------------------------------------------------------------------
// In-place row softmax over 1024 elems. One block (4 waves) per row.
// ---------------------------------------------------------------------------
__global__ __launch_bounds__(256)
void softmax_kernel(float* __restrict__ attn)
{
    const int tid = threadIdx.x;
    float* p = attn + (size_t)blockIdx.x * SS;
    float4 v = ((const float4*)p)[tid];
    float m = fmaxf(fmaxf(v.x, v.y), fmaxf(v.z, v.w));
#pragma unroll
    for (int off = 32; off > 0; off >>= 1)
        m = fmaxf(m, __shfl_xor(m, off, 64));
    __shared__ float redm[4];
    __shared__ float reds[4];
    const int wid = tid >> 6, lane = tid & 63;
    if (lane == 0) redm[wid] = m;
    __syncthreads();
    m = fmaxf(fmaxf(redm[0], redm[1]), fmaxf(redm[2], redm[3]));
    v.x = __expf(v.x - m); v.y = __expf(v.y - m);
    v.z = __expf(v.z - m); v.w = __expf(v.w - m);
    float s = v.x + v.y + v.z + v.w;
#pragma unroll
    for (int off = 32; off > 0; off >>= 1)
        s += __shfl_xor(s, off, 64);
    if (lane == 0) reds[wid] = s;
    __syncthreads();
    s = reds[0] + reds[1] + reds[2] + reds[3];
    const float inv = 1.f / s;
    v.x *= inv; v.y *= inv; v.z *= inv; v.w *= inv;
    ((float4*)p)[tid] = v;
}

// ---------------------------------------------------------------------------
// ctx[b, i, h*64+d] = sum_j attn[bh,i,j] * v[bh,j,d]    (M=1024, N=64, K=1024)
// ---------------------------------------------------------------------------
__global__ __launch_bounds__(256)
void pv_kernel(const float* __restrict__ attn, const float* __restrict__ vh,
               float* __restrict__ ctx)
{
    __shared__ float As[16][65];
    __shared__ float Bs[16][65];
    const int tid = threadIdx.x;
    const int tx = tid & 15, ty = tid >> 4;
    const int i0 = blockIdx.x * 64;
    const int bh = blockIdx.y;
    const int b_ = bh >> 4, h = bh & 15;
    const float* arow = attn + (size_t)bh * SS * SS;
    const float* vv = vh + (size_t)bh * SS * DD;
    float acc[4][4] = {{0.f}};
    for (int k0 = 0; k0 < SS; k0 += 16) {
#pragma unroll
        for (int t = 0; t < 4; ++t) {
            const int idx = tid + t * 256;
            const int ra = idx >> 4, ca = idx & 15;
            As[ca][ra] = arow[(size_t)(i0 + ra) * SS + k0 + ca];
            const int rb = idx >> 6, cb = idx & 63;
            Bs[rb][cb] = vv[(size_t)(k0 + rb) * DD + cb];
        }
        __syncthreads();
#pragma unroll
        for (int kk = 0; kk < 16; ++kk) {
            float a[4], b[4];
#pragma unroll
            for (int i = 0; i < 4; ++i) a[i] = As[kk][ty * 4 + i];
#pragma unroll
            for (int j = 0; j < 4; ++j) b[j] = Bs[kk][tx * 4 + j];
#pragma unroll
            for (int i = 0; i < 4; ++i)
#pragma unroll
                for (int j = 0; j < 4; ++j)
                    acc[i][j] = fmaf(a[i], b[j], acc[i][j]);
        }
        __syncthreads();
    }
#pragma unroll
    for (int i = 0; i < 4; ++i) {
        const int gi = i0 + ty * 4 + i;
        float4 o = {acc[i][0], acc[i][1], acc[i][2], acc[i][3]};
        *(float4*)(ctx + ((size_t)b_ * SS + gi) * EE + h * DD + tx * 4) = o;
    }
}

extern "C" void kernel_launch(void* const* d_in, const int* in_sizes, int n_in,
                              void* d_out, int out_size, void* d_ws, size_t ws_size,
                              hipStream_t stream)
{
    const float* query = (const float*)d_in[0];
    const float* key_  = (const float*)d_in[1];
    const float* value = (const float*)d_in[2];
    const int*   mask  = (const int*)d_in[3];
    const float* Wq = (const float*)d_in[4];
    const float* bq = (const float*)d_in[5];
    const float* Wk = (const float*)d_in[6];
    const float* bk = (const float*)d_in[7];
    const float* Wv = (const float*)d_in[8];
    const float* bv = (const float*)d_in[9];
    const float* Wo = (const float*)d_in[10];
    const float* bo = (const float*)d_in[11];
    const float* emb = (const float*)d_in[12];

    float* out  = (float*)d_out;                          // [B,S,E]
    float* attn = (float*)d_out + (size_t)BB * SS * EE;   // [B,H,S,S]

    float* qh   = (float*)d_ws;                           // [B,H,S,D]
    float* kh   = qh + (size_t)BB * HH * SS * DD;
    float* vh   = kh + (size_t)BB * HH * SS * DD;
    float* prel = vh + (size_t)BB * HH * SS * DD;         // [B*H*S, 129]
    float* ctx  = kh;  // k-heads dead after scores; reuse as merged [B,S,E]

    dim3 blk(256);
    dim3 gproj(64, 16);
    gemm_bias_kernel<<<gproj, blk, 0, stream>>>(query, Wq, bq, qh, 1);
    gemm_bias_kernel<<<gproj, blk, 0, stream>>>(key_,  Wk, bk, kh, 1);
    gemm_bias_kernel<<<gproj, blk, 0, stream>>>(value, Wv, bv, vh, 1);
    relproj_kernel<<<dim3(1024), blk, 0, stream>>>(qh, emb, prel);
    scores_kernel<<<dim3(16, 16, 64), blk, 0, stream>>>(qh, kh, prel, mask, attn);
    softmax_kernel<<<dim3(65536), blk, 0, stream>>>(attn);
    pv_kernel<<<dim3(16, 64), blk, 0, stream>>>(attn, vh, ctx);
    gemm_bias_kernel<<<gproj, blk, 0, stream>>>(ctx, Wo, bo, out, 0);
}

// Round 2
// 663.827 us; speedup vs baseline: 1.8709x; 1.8709x over previous
//
#include <hip/hip_runtime.h>
#include <math.h>

#define BB 4
#define SS 1024
#define EE 1024
#define HH 16
#define DD 64
#define RR 129

typedef __attribute__((ext_vector_type(4))) float f32x4;
typedef __attribute__((ext_vector_type(8))) short bf8;   // 8 bf16 = 4 VGPR (MFMA A/B frag)
typedef __attribute__((ext_vector_type(4))) short s4v;   // 4 bf16 = 8B

#define MFMA(a, b, c) __builtin_amdgcn_mfma_f32_16x16x32_bf16(a, b, c, 0, 0, 0)

__device__ __forceinline__ float bf2f(unsigned short u) {
    return __uint_as_float(((unsigned)u) << 16);
}
__device__ __forceinline__ unsigned short f2bf(float x) {  // RNE
    unsigned u = __float_as_uint(x);
    return (unsigned short)((u + 0x7fffu + ((u >> 16) & 1u)) >> 16);
}

// ---------------------------------------------------------------------------
// Weight transpose+split: W[K][N] fp32 -> Wt_hi/lo[N][K] bf16.
// ---------------------------------------------------------------------------
__global__ __launch_bounds__(256, 4)
void wtrans_kernel(const float* __restrict__ Wq, const float* __restrict__ Wk,
                   const float* __restrict__ Wv, const float* __restrict__ Wo,
                   unsigned short* __restrict__ wt_hi, unsigned short* __restrict__ wt_lo)
{
    __shared__ float T[64][65];
    const int w = blockIdx.z;
    const float* W = w == 0 ? Wq : (w == 1 ? Wk : (w == 2 ? Wv : Wo));
    const int n0 = blockIdx.x * 64, k0 = blockIdx.y * 64;
    const int tid = threadIdx.x;
#pragma unroll
    for (int i = 0; i < 4; ++i) {
        int c = tid + 256 * i; int r = c >> 4, c4 = c & 15;
        f32x4 v = *(const f32x4*)(W + (size_t)(k0 + r) * EE + n0 + c4 * 4);
        T[r][c4 * 4 + 0] = v.x; T[r][c4 * 4 + 1] = v.y;
        T[r][c4 * 4 + 2] = v.z; T[r][c4 * 4 + 3] = v.w;
    }
    __syncthreads();
#pragma unroll
    for (int i = 0; i < 4; ++i) {
        int c = tid + 256 * i; int r = c >> 4, c4 = c & 15;   // r = n_local, c4 = k group
        float x0 = T[c4 * 4 + 0][r], x1 = T[c4 * 4 + 1][r];
        float x2 = T[c4 * 4 + 2][r], x3 = T[c4 * 4 + 3][r];
        unsigned short h0 = f2bf(x0), h1 = f2bf(x1), h2 = f2bf(x2), h3 = f2bf(x3);
        unsigned short l0 = f2bf(x0 - bf2f(h0)), l1 = f2bf(x1 - bf2f(h1));
        unsigned short l2 = f2bf(x2 - bf2f(h2)), l3 = f2bf(x3 - bf2f(h3));
        size_t o = (size_t)w * 1048576 + (size_t)(n0 + r) * 1024 + k0 + c4 * 4;
        *(s4v*)&wt_hi[o] = (s4v){(short)h0, (short)h1, (short)h2, (short)h3};
        *(s4v*)&wt_lo[o] = (s4v){(short)l0, (short)l1, (short)l2, (short)l3};
    }
}

// ---------------------------------------------------------------------------
// Split-bf16 MFMA GEMM body. 128x128 tile, BK=64, 4 waves (2x2), 4x4 frags.
// LDS tiles are [row][64] bf16 with 16B-chunk XOR swizzle (chunk ^= row&7).
// ASRC: 0 = fp32 A source (convert in-kernel), 1 = bf16 hi/lo pair A source.
// EPI:  0 = heads-split hi/lo bf16 output, 1 = plain fp32 output (+bias).
// ---------------------------------------------------------------------------
template<int ASRC, int EPI>
__device__ __forceinline__ void gemm_body(
    const float* __restrict__ Af,
    const unsigned short* __restrict__ Ah_g, const unsigned short* __restrict__ Al_g,
    const unsigned short* __restrict__ Bh_g, const unsigned short* __restrict__ Bl_g,
    const float* __restrict__ bias,
    float* __restrict__ Yf, unsigned short* __restrict__ Yh, unsigned short* __restrict__ Yl,
    unsigned short* As_h, unsigned short* As_l, unsigned short* Bs_h, unsigned short* Bs_l,
    int m0, int n0)
{
    const int tid = threadIdx.x, lane = tid & 63, wid = tid >> 6;
    const int wm = (wid >> 1) * 64, wn = (wid & 1) * 64;
    f32x4 zero4 = {0.f, 0.f, 0.f, 0.f};
    f32x4 acc[4][4];
#pragma unroll
    for (int a = 0; a < 4; ++a)
#pragma unroll
        for (int b = 0; b < 4; ++b) acc[a][b] = zero4;

    for (int kt = 0; kt < 1024; kt += 64) {
        __syncthreads();
        if (ASRC == 0) {
#pragma unroll
            for (int i = 0; i < 8; ++i) {
                int c = tid + 256 * i; int r = c >> 4, c4 = c & 15;
                f32x4 v = *(const f32x4*)(Af + (size_t)(m0 + r) * 1024 + kt + c4 * 4);
                unsigned short h0 = f2bf(v.x), h1 = f2bf(v.y), h2 = f2bf(v.z), h3 = f2bf(v.w);
                unsigned short l0 = f2bf(v.x - bf2f(h0)), l1 = f2bf(v.y - bf2f(h1));
                unsigned short l2 = f2bf(v.z - bf2f(h2)), l3 = f2bf(v.w - bf2f(h3));
                int off = r * 64 + (((c4 >> 1) ^ (r & 7)) * 8) + (c4 & 1) * 4;
                *(s4v*)&As_h[off] = (s4v){(short)h0, (short)h1, (short)h2, (short)h3};
                *(s4v*)&As_l[off] = (s4v){(short)l0, (short)l1, (short)l2, (short)l3};
            }
        } else {
#pragma unroll
            for (int i = 0; i < 4; ++i) {
                int c = tid + 256 * i; int r = c >> 3, cc = c & 7;
                int off = r * 64 + ((cc ^ (r & 7)) * 8);
                *(bf8*)&As_h[off] = *(const bf8*)(Ah_g + (size_t)(m0 + r) * 1024 + kt + cc * 8);
                *(bf8*)&As_l[off] = *(const bf8*)(Al_g + (size_t)(m0 + r) * 1024 + kt + cc * 8);
            }
        }
#pragma unroll
        for (int i = 0; i < 4; ++i) {
            int c = tid + 256 * i; int r = c >> 3, cc = c & 7;
            int off = r * 64 + ((cc ^ (r & 7)) * 8);
            *(bf8*)&Bs_h[off] = *(const bf8*)(Bh_g + (size_t)(n0 + r) * 1024 + kt + cc * 8);
            *(bf8*)&Bs_l[off] = *(const bf8*)(Bl_g + (size_t)(n0 + r) * 1024 + kt + cc * 8);
        }
        __syncthreads();
#pragma unroll
        for (int ks = 0; ks < 2; ++ks) {
            bf8 ah[4], al[4], bh[4], bl[4];
#pragma unroll
            for (int f = 0; f < 4; ++f) {
                int ra = wm + f * 16 + (lane & 15);
                int ca = (ks * 4 + (lane >> 4)) ^ (ra & 7);
                ah[f] = *(const bf8*)&As_h[ra * 64 + ca * 8];
                al[f] = *(const bf8*)&As_l[ra * 64 + ca * 8];
                int rb = wn + f * 16 + (lane & 15);
                int cb = (ks * 4 + (lane >> 4)) ^ (rb & 7);
                bh[f] = *(const bf8*)&Bs_h[rb * 64 + cb * 8];
                bl[f] = *(const bf8*)&Bs_l[rb * 64 + cb * 8];
            }
#pragma unroll
            for (int fi = 0; fi < 4; ++fi)
#pragma unroll
                for (int fj = 0; fj < 4; ++fj) {
                    acc[fi][fj] = MFMA(ah[fi], bh[fj], acc[fi][fj]);
                    acc[fi][fj] = MFMA(al[fi], bh[fj], acc[fi][fj]);
                    acc[fi][fj] = MFMA(ah[fi], bl[fj], acc[fi][fj]);
                }
        }
    }
    // epilogue: C/D layout (m89): col = lane&15, row = (lane>>4)*4 + reg
#pragma unroll
    for (int fi = 0; fi < 4; ++fi)
#pragma unroll
        for (int fj = 0; fj < 4; ++fj)
#pragma unroll
            for (int rg = 0; rg < 4; ++rg) {
                int m = m0 + wm + fi * 16 + ((lane >> 4) << 2) + rg;
                int n = n0 + wn + fj * 16 + (lane & 15);
                float val = acc[fi][fj][rg] + bias[n];
                if (EPI == 0) {
                    int b = m >> 10, s = m & 1023, h = n >> 6, d = n & 63;
                    size_t o = (((size_t)(b * 16 + h)) * 1024 + s) * 64 + d;
                    unsigned short hv = f2bf(val);
                    unsigned short lv = f2bf(val - bf2f(hv));
                    Yh[o] = hv; Yl[o] = lv;
                } else {
                    Yf[(size_t)m * 1024 + n] = val;
                }
            }
}

__global__ __launch_bounds__(256, 2)
void proj_qkv_kernel(const float* __restrict__ q_in, const float* __restrict__ k_in,
                     const float* __restrict__ v_in,
                     const unsigned short* __restrict__ wt_hi, const unsigned short* __restrict__ wt_lo,
                     const float* __restrict__ bq, const float* __restrict__ bk,
                     const float* __restrict__ bv,
                     unsigned short* qh_hi, unsigned short* qh_lo,
                     unsigned short* kh_hi, unsigned short* kh_lo,
                     unsigned short* vh_hi, unsigned short* vh_lo)
{
    __shared__ __align__(16) unsigned short As_h[128 * 64], As_l[128 * 64];
    __shared__ __align__(16) unsigned short Bs_h[128 * 64], Bs_l[128 * 64];
    const int z = blockIdx.z;
    const float* X = z == 0 ? q_in : (z == 1 ? k_in : v_in);
    const float* bias = z == 0 ? bq : (z == 1 ? bk : bv);
    unsigned short* Yh = z == 0 ? qh_hi : (z == 1 ? kh_hi : vh_hi);
    unsigned short* Yl = z == 0 ? qh_lo : (z == 1 ? kh_lo : vh_lo);
    gemm_body<0, 0>(X, nullptr, nullptr,
                    wt_hi + (size_t)z * 1048576, wt_lo + (size_t)z * 1048576,
                    bias, nullptr, Yh, Yl, As_h, As_l, Bs_h, Bs_l,
                    blockIdx.x * 128, blockIdx.y * 128);
}

__global__ __launch_bounds__(256, 2)
void outproj_kernel(const unsigned short* __restrict__ ctx_hi, const unsigned short* __restrict__ ctx_lo,
                    const unsigned short* __restrict__ wo_hi, const unsigned short* __restrict__ wo_lo,
                    const float* __restrict__ bo, float* __restrict__ out)
{
    __shared__ __align__(16) unsigned short As_h[128 * 64], As_l[128 * 64];
    __shared__ __align__(16) unsigned short Bs_h[128 * 64], Bs_l[128 * 64];
    gemm_body<1, 1>(nullptr, ctx_hi, ctx_lo, wo_hi, wo_lo, bo, out, nullptr, nullptr,
                    As_h, As_l, Bs_h, Bs_l, blockIdx.x * 128, blockIdx.y * 128);
}

// ---------------------------------------------------------------------------
// V transpose: vh[bh][s][d] (ushort) -> vt[bh][d][s]. z: 0=hi,1=lo buffers.
// ---------------------------------------------------------------------------
__global__ __launch_bounds__(256, 4)
void vtrans_kernel(const unsigned short* __restrict__ vh_hi, const unsigned short* __restrict__ vh_lo,
                   unsigned short* __restrict__ vt_hi, unsigned short* __restrict__ vt_lo)
{
    __shared__ unsigned short T[64][72];
    const unsigned short* src = blockIdx.z ? vh_lo : vh_hi;
    unsigned short* dst = blockIdx.z ? vt_lo : vt_hi;
    const int st = blockIdx.x * 64, bh = blockIdx.y, tid = threadIdx.x;
#pragma unroll
    for (int i = 0; i < 4; ++i) {
        int c = tid + 256 * i; int r = c >> 4, d4 = c & 15;
        s4v v = *(const s4v*)(src + ((size_t)bh * 1024 + st + r) * 64 + d4 * 4);
        T[r][d4 * 4 + 0] = (unsigned short)v.x; T[r][d4 * 4 + 1] = (unsigned short)v.y;
        T[r][d4 * 4 + 2] = (unsigned short)v.z; T[r][d4 * 4 + 3] = (unsigned short)v.w;
    }
    __syncthreads();
#pragma unroll
    for (int i = 0; i < 4; ++i) {
        int c = tid + 256 * i; int r = c >> 4, s4_ = c & 15;  // r = d row
        s4v o = {(short)T[s4_ * 4 + 0][r], (short)T[s4_ * 4 + 1][r],
                 (short)T[s4_ * 4 + 2][r], (short)T[s4_ * 4 + 3][r]};
        *(s4v*)(dst + ((size_t)bh * 64 + r) * 1024 + st + s4_ * 4) = o;
    }
}

// ---------------------------------------------------------------------------
// prel[row][r] = q_hi[row,:64] . emb[r,:64]  (row = bh*1024+s), bf16 out.
// ---------------------------------------------------------------------------
__global__ __launch_bounds__(256, 2)
void relproj_kernel(const unsigned short* __restrict__ qh_hi, const float* __restrict__ emb,
                    unsigned short* __restrict__ prel)
{
    __shared__ float se[RR][68];
    __shared__ float sq[128][68];
    const int tid = threadIdx.x;
    const size_t row0 = (size_t)blockIdx.x * 128;
    for (int i = tid; i < RR * 64; i += 256) { int r = i >> 6, d = i & 63; se[r][d] = emb[i]; }
#pragma unroll
    for (int i = 0; i < 8; ++i) {
        int c = tid + 256 * i; int r = c >> 4, d4 = c & 15;
        s4v v = *(const s4v*)(qh_hi + (row0 + r) * 64 + d4 * 4);
        sq[r][d4 * 4 + 0] = bf2f((unsigned short)v.x);
        sq[r][d4 * 4 + 1] = bf2f((unsigned short)v.y);
        sq[r][d4 * 4 + 2] = bf2f((unsigned short)v.z);
        sq[r][d4 * 4 + 3] = bf2f((unsigned short)v.w);
    }
    __syncthreads();
    for (int idx = tid; idx < 128 * RR; idx += 256) {
        int r = idx / RR, c = idx - r * RR;
        const float* a = sq[r];
        const float* b = se[c];
        float s = 0.f;
#pragma unroll
        for (int d = 0; d < 64; ++d) s = fmaf(a[d], b[d], s);
        prel[(row0 + r) * RR + c] = f2bf(s);
    }
}

// ---------------------------------------------------------------------------
// Scores: raw s = QK^T/8 + relbias (masked), written fp32 into attn region.
// Fused online row max / sum-exp -> rowm, rowsum. Split-bf16 MFMA.
// Block: 128 i-rows x all j; 4 waves 2x2 (wm: i-half, wn: j-half per tile).
// ---------------------------------------------------------------------------
__global__ __launch_bounds__(256, 2)
void scores_kernel(const unsigned short* __restrict__ qh_hi, const unsigned short* __restrict__ qh_lo,
                   const unsigned short* __restrict__ kh_hi, const unsigned short* __restrict__ kh_lo,
                   const unsigned short* __restrict__ prel, const int* __restrict__ mask,
                   float* __restrict__ attn, float* __restrict__ rowm, float* __restrict__ rowsum)
{
    __shared__ __align__(16) unsigned short Qh[128 * 64], Ql[128 * 64];
    __shared__ __align__(16) unsigned short Kh[128 * 64], Kl[128 * 64];
    __shared__ float Sm[2][2][64], Ss[2][2][64];
    const int tid = threadIdx.x, lane = tid & 63, wid = tid >> 6;
    const int wm = (wid >> 1) * 64, wn = (wid & 1) * 64;
    const int i0 = blockIdx.x * 128, bh = blockIdx.y, b = bh >> 4;

    const unsigned short* qbh = qh_hi + ((size_t)bh * 1024 + i0) * 64;
    const unsigned short* qbl = qh_lo + ((size_t)bh * 1024 + i0) * 64;
#pragma unroll
    for (int i = 0; i < 4; ++i) {
        int c = tid + 256 * i; int r = c >> 3, cc = c & 7;
        int off = r * 64 + ((cc ^ (r & 7)) * 8);
        *(bf8*)&Qh[off] = *(const bf8*)(qbh + r * 64 + cc * 8);
        *(bf8*)&Ql[off] = *(const bf8*)(qbl + r * 64 + cc * 8);
    }
    float rm[16], rs[16];
#pragma unroll
    for (int i = 0; i < 16; ++i) { rm[i] = -3.0e38f; rs[i] = 0.f; }

    for (int jt = 0; jt < 8; ++jt) {
        __syncthreads();
        const unsigned short* kbh = kh_hi + ((size_t)bh * 1024 + jt * 128) * 64;
        const unsigned short* kbl = kh_lo + ((size_t)bh * 1024 + jt * 128) * 64;
#pragma unroll
        for (int i = 0; i < 4; ++i) {
            int c = tid + 256 * i; int r = c >> 3, cc = c & 7;
            int off = r * 64 + ((cc ^ (r & 7)) * 8);
            *(bf8*)&Kh[off] = *(const bf8*)(kbh + r * 64 + cc * 8);
            *(bf8*)&Kl[off] = *(const bf8*)(kbl + r * 64 + cc * 8);
        }
        __syncthreads();
        f32x4 zero4 = {0.f, 0.f, 0.f, 0.f};
        f32x4 acc[4][4];
#pragma unroll
        for (int a = 0; a < 4; ++a)
#pragma unroll
            for (int c = 0; c < 4; ++c) acc[a][c] = zero4;
#pragma unroll
        for (int ks = 0; ks < 2; ++ks) {
            bf8 ah[4], al[4], bhf[4], blf[4];
#pragma unroll
            for (int f = 0; f < 4; ++f) {
                int ra = wm + f * 16 + (lane & 15);
                int ca = (ks * 4 + (lane >> 4)) ^ (ra & 7);
                ah[f] = *(const bf8*)&Qh[ra * 64 + ca * 8];
                al[f] = *(const bf8*)&Ql[ra * 64 + ca * 8];
                int rb = wn + f * 16 + (lane & 15);
                int cb = (ks * 4 + (lane >> 4)) ^ (rb & 7);
                bhf[f] = *(const bf8*)&Kh[rb * 64 + cb * 8];
                blf[f] = *(const bf8*)&Kl[rb * 64 + cb * 8];
            }
#pragma unroll
            for (int fi = 0; fi < 4; ++fi)
#pragma unroll
                for (int fj = 0; fj < 4; ++fj) {
                    acc[fi][fj] = MFMA(ah[fi], bhf[fj], acc[fi][fj]);
                    acc[fi][fj] = MFMA(al[fi], bhf[fj], acc[fi][fj]);
                    acc[fi][fj] = MFMA(ah[fi], blf[fj], acc[fi][fj]);
                }
        }
        // post: bias + mask + raw write + online stats
#pragma unroll
        for (int fi = 0; fi < 4; ++fi)
#pragma unroll
            for (int rg = 0; rg < 4; ++rg) {
                int ii = i0 + wm + fi * 16 + ((lane >> 4) << 2) + rg;
                const unsigned short* prow = prel + ((size_t)bh * 1024 + ii) * RR;
                const int* mrow = mask + (size_t)b * 1048576 + (size_t)ii * 1024;
                float s4[4]; float tmax = -3.0e38f;
#pragma unroll
                for (int fj = 0; fj < 4; ++fj) {
                    int jj = jt * 128 + wn + fj * 16 + (lane & 15);
                    int dd = ii - jj; dd = dd < -64 ? -64 : (dd > 64 ? 64 : dd);
                    float s = acc[fi][fj][rg] * 0.125f + bf2f(prow[dd + 64]);
                    if (mrow[jj] == 0) s = -1.0e30f;
                    attn[((size_t)bh * 1024 + ii) * 1024 + jj] = s;
                    s4[fj] = s; tmax = fmaxf(tmax, s);
                }
#pragma unroll
                for (int mk = 1; mk < 16; mk <<= 1)
                    tmax = fmaxf(tmax, __shfl_xor(tmax, mk, 64));
                int idx = fi * 4 + rg;
                float nm = fmaxf(rm[idx], tmax);
                float p = __expf(s4[0] - nm) + __expf(s4[1] - nm)
                        + __expf(s4[2] - nm) + __expf(s4[3] - nm);
#pragma unroll
                for (int mk = 1; mk < 16; mk <<= 1)
                    p += __shfl_xor(p, mk, 64);
                rs[idx] = rs[idx] * __expf(rm[idx] - nm) + p;
                rm[idx] = nm;
            }
    }
    // combine the two j-half waves per i-row
#pragma unroll
    for (int fi = 0; fi < 4; ++fi)
#pragma unroll
        for (int rg = 0; rg < 4; ++rg) {
            int rl = fi * 16 + ((lane >> 4) << 2) + rg;
            if ((lane & 15) == 0) {
                Sm[wid >> 1][wid & 1][rl] = rm[fi * 4 + rg];
                Ss[wid >> 1][wid & 1][rl] = rs[fi * 4 + rg];
            }
        }
    __syncthreads();
    if (tid < 128) {
        int wmi = tid >> 6, rl = tid & 63;
        float m0_ = Sm[wmi][0][rl], m1_ = Sm[wmi][1][rl];
        float mm = fmaxf(m0_, m1_);
        float ss = Ss[wmi][0][rl] * __expf(m0_ - mm) + Ss[wmi][1][rl] * __expf(m1_ - mm);
        rowm[(size_t)bh * 1024 + i0 + tid] = mm;
        rowsum[(size_t)bh * 1024 + i0 + tid] = ss;
    }
}

// ---------------------------------------------------------------------------
// PV: normalize raw scores in place (writes final attn weights), split to
// hi/lo bf16 in LDS, MFMA against transposed V. ctx written hi/lo merged.
// Block: 128 i x 64 d; 4 waves stacked on i (32 rows each); K tiles of 64 j.
// ---------------------------------------------------------------------------
__global__ __launch_bounds__(256, 2)
void pv_kernel(float* __restrict__ attn,
               const unsigned short* __restrict__ vt_hi, const unsigned short* __restrict__ vt_lo,
               const float* __restrict__ rowm, const float* __restrict__ rowsum,
               unsigned short* __restrict__ ctx_hi, unsigned short* __restrict__ ctx_lo)
{
    __shared__ __align__(16) unsigned short Ah[128 * 64], Al[128 * 64];
    __shared__ __align__(16) unsigned short Bh_[64 * 64], Bl_[64 * 64];
    const int tid = threadIdx.x, lane = tid & 63, wid = tid >> 6;
    const int i0 = blockIdx.x * 128, bh = blockIdx.y;

    float m8[8], inv8[8];
#pragma unroll
    for (int i = 0; i < 8; ++i) {
        int r = (tid >> 4) + 16 * i;
        m8[i] = rowm[(size_t)bh * 1024 + i0 + r];
        inv8[i] = 1.f / rowsum[(size_t)bh * 1024 + i0 + r];
    }
    f32x4 zero4 = {0.f, 0.f, 0.f, 0.f};
    f32x4 acc[2][4];
#pragma unroll
    for (int a = 0; a < 2; ++a)
#pragma unroll
        for (int c = 0; c < 4; ++c) acc[a][c] = zero4;

    for (int jt = 0; jt < 16; ++jt) {
        __syncthreads();
#pragma unroll
        for (int i = 0; i < 8; ++i) {
            int c = tid + 256 * i; int r = c >> 4, c4 = c & 15;
            size_t g = ((size_t)bh * 1024 + i0 + r) * 1024 + jt * 64 + c4 * 4;
            f32x4 v = *(f32x4*)(attn + g);
            float mm = m8[i], iv = inv8[i];
            v.x = __expf(v.x - mm) * iv; v.y = __expf(v.y - mm) * iv;
            v.z = __expf(v.z - mm) * iv; v.w = __expf(v.w - mm) * iv;
            *(f32x4*)(attn + g) = v;   // final attention weights
            unsigned short h0 = f2bf(v.x), h1 = f2bf(v.y), h2 = f2bf(v.z), h3 = f2bf(v.w);
            unsigned short l0 = f2bf(v.x - bf2f(h0)), l1 = f2bf(v.y - bf2f(h1));
            unsigned short l2 = f2bf(v.z - bf2f(h2)), l3 = f2bf(v.w - bf2f(h3));
            int off = r * 64 + (((c4 >> 1) ^ (r & 7)) * 8) + (c4 & 1) * 4;
            *(s4v*)&Ah[off] = (s4v){(short)h0, (short)h1, (short)h2, (short)h3};
            *(s4v*)&Al[off] = (s4v){(short)l0, (short)l1, (short)l2, (short)l3};
        }
#pragma unroll
        for (int i = 0; i < 2; ++i) {
            int c = tid + 256 * i; int r = c >> 3, cc = c & 7;
            int off = r * 64 + ((cc ^ (r & 7)) * 8);
            *(bf8*)&Bh_[off] = *(const bf8*)(vt_hi + ((size_t)bh * 64 + r) * 1024 + jt * 64 + cc * 8);
            *(bf8*)&Bl_[off] = *(const bf8*)(vt_lo + ((size_t)bh * 64 + r) * 1024 + jt * 64 + cc * 8);
        }
        __syncthreads();
#pragma unroll
        for (int ks = 0; ks < 2; ++ks) {
            bf8 ah[2], al[2], bhf[4], blf[4];
#pragma unroll
            for (int f = 0; f < 2; ++f) {
                int ra = wid * 32 + f * 16 + (lane & 15);
                int ca = (ks * 4 + (lane >> 4)) ^ (ra & 7);
                ah[f] = *(const bf8*)&Ah[ra * 64 + ca * 8];
                al[f] = *(const bf8*)&Al[ra * 64 + ca * 8];
            }
#pragma unroll
            for (int f = 0; f < 4; ++f) {
                int rb = f * 16 + (lane & 15);
                int cb = (ks * 4 + (lane >> 4)) ^ (rb & 7);
                bhf[f] = *(const bf8*)&Bh_[rb * 64 + cb * 8];
                blf[f] = *(const bf8*)&Bl_[rb * 64 + cb * 8];
            }
#pragma unroll
            for (int fi = 0; fi < 2; ++fi)
#pragma unroll
                for (int fj = 0; fj < 4; ++fj) {
                    acc[fi][fj] = MFMA(ah[fi], bhf[fj], acc[fi][fj]);
                    acc[fi][fj] = MFMA(al[fi], bhf[fj], acc[fi][fj]);
                    acc[fi][fj] = MFMA(ah[fi], blf[fj], acc[fi][fj]);
                }
        }
    }
    const int b = bh >> 4, h = bh & 15;
#pragma unroll
    for (int fi = 0; fi < 2; ++fi)
#pragma unroll
        for (int fj = 0; fj < 4; ++fj)
#pragma unroll
            for (int rg = 0; rg < 4; ++rg) {
                int ii = i0 + wid * 32 + fi * 16 + ((lane >> 4) << 2) + rg;
                int d = fj * 16 + (lane & 15);
                float val = acc[fi][fj][rg];
                size_t o = ((size_t)b * 1024 + ii) * 1024 + h * 64 + d;
                unsigned short hv = f2bf(val);
                unsigned short lv = f2bf(val - bf2f(hv));
                ctx_hi[o] = hv; ctx_lo[o] = lv;
            }
}

extern "C" void kernel_launch(void* const* d_in, const int* in_sizes, int n_in,
                              void* d_out, int out_size, void* d_ws, size_t ws_size,
                              hipStream_t stream)
{
    const float* query = (const float*)d_in[0];
    const float* key_  = (const float*)d_in[1];
    const float* value = (const float*)d_in[2];
    const int*   mask  = (const int*)d_in[3];
    const float* Wq = (const float*)d_in[4];
    const float* bq = (const float*)d_in[5];
    const float* Wk = (const float*)d_in[6];
    const float* bk = (const float*)d_in[7];
    const float* Wv = (const float*)d_in[8];
    const float* bv = (const float*)d_in[9];
    const float* Wo = (const float*)d_in[10];
    const float* bo = (const float*)d_in[11];
    const float* emb = (const float*)d_in[12];

    // workspace layout (84.0 MB; round-1 usage proved >= 84.1 MB available)
    unsigned short* wt_hi = (unsigned short*)d_ws;           // [4][1024][1024]
    unsigned short* wt_lo = wt_hi + (size_t)4 * 1048576;
    unsigned short* qh_hi = wt_lo + (size_t)4 * 1048576;     // [64][1024][64]
    unsigned short* qh_lo = qh_hi + 4194304;
    unsigned short* kh_hi = qh_lo + 4194304;
    unsigned short* kh_lo = kh_hi + 4194304;
    unsigned short* vt_hi = kh_lo + 4194304;                 // [64][64][1024]
    unsigned short* vt_lo = vt_hi + 4194304;
    unsigned short* prel  = vt_lo + 4194304;                 // [65536][129]
    // stats overlay the (dead-after-projection) Wq^T region:
    float* rowm   = (float*)d_ws;                            // [65536]
    float* rowsum = rowm + 65536;
    // ctx reuses q-heads (dead after scores/relproj):
    unsigned short* ctx_hi = qh_hi;
    unsigned short* ctx_lo = qh_lo;
    // v-heads scratch lives in the out region (written last):
    unsigned short* vh_hi = (unsigned short*)d_out;          // 16 MB region
    unsigned short* vh_lo = vh_hi + 4194304;

    float* out  = (float*)d_out;
    float* attn = (float*)d_out + 4194304;

    dim3 blk(256);
    wtrans_kernel<<<dim3(16, 16, 4), blk, 0, stream>>>(Wq, Wk, Wv, Wo, wt_hi, wt_lo);
    proj_qkv_kernel<<<dim3(32, 8, 3), blk, 0, stream>>>(query, key_, value, wt_hi, wt_lo,
                                                        bq, bk, bv, qh_hi, qh_lo,
                                                        kh_hi, kh_lo, vh_hi, vh_lo);
    vtrans_kernel<<<dim3(16, 64, 2), blk, 0, stream>>>(vh_hi, vh_lo, vt_hi, vt_lo);
    relproj_kernel<<<dim3(512), blk, 0, stream>>>(qh_hi, emb, prel);
    scores_kernel<<<dim3(8, 64), blk, 0, stream>>>(qh_hi, qh_lo, kh_hi, kh_lo, prel, mask,
                                                   attn, rowm, rowsum);
    pv_kernel<<<dim3(8, 64), blk, 0, stream>>>(attn, vt_hi, vt_lo, rowm, rowsum, ctx_hi, ctx_lo);
    outproj_kernel<<<dim3(32, 8), blk, 0, stream>>>(ctx_hi, ctx_lo,
                                                    wt_hi + (size_t)3 * 1048576,
                                                    wt_lo + (size_t)3 * 1048576, bo, out);
}

// Round 3
// 487.588 us; speedup vs baseline: 2.5472x; 1.3615x over previous
//
#include <hip/hip_runtime.h>
#include <math.h>

#define BB 4
#define SS 1024
#define EE 1024
#define HH 16
#define DD 64
#define RR 129
#define PRELW 130   // prel row stride (ushorts): 260B rows, 4B-aligned, bank-clean

typedef __attribute__((ext_vector_type(4))) float f32x4;
typedef __attribute__((ext_vector_type(8))) short bf8;   // 8 bf16 = 4 VGPR (MFMA A/B frag)
typedef __attribute__((ext_vector_type(4))) short s4v;   // 4 bf16 = 8B

#define MFMA(a, b, c) __builtin_amdgcn_mfma_f32_16x16x32_bf16(a, b, c, 0, 0, 0)

__device__ __forceinline__ float bf2f(unsigned short u) {
    return __uint_as_float(((unsigned)u) << 16);
}
__device__ __forceinline__ unsigned short f2bf(float x) {  // RNE
    unsigned u = __float_as_uint(x);
    return (unsigned short)((u + 0x7fffu + ((u >> 16) & 1u)) >> 16);
}

// ---------------------------------------------------------------------------
// Weight transpose+split: W[K][N] fp32 -> Wt_hi/lo[N][K] bf16.
// ---------------------------------------------------------------------------
__global__ __launch_bounds__(256, 4)
void wtrans_kernel(const float* __restrict__ Wq, const float* __restrict__ Wk,
                   const float* __restrict__ Wv, const float* __restrict__ Wo,
                   unsigned short* __restrict__ wt_hi, unsigned short* __restrict__ wt_lo)
{
    __shared__ float T[64][65];
    const int w = blockIdx.z;
    const float* W = w == 0 ? Wq : (w == 1 ? Wk : (w == 2 ? Wv : Wo));
    const int n0 = blockIdx.x * 64, k0 = blockIdx.y * 64;
    const int tid = threadIdx.x;
#pragma unroll
    for (int i = 0; i < 4; ++i) {
        int c = tid + 256 * i; int r = c >> 4, c4 = c & 15;
        f32x4 v = *(const f32x4*)(W + (size_t)(k0 + r) * EE + n0 + c4 * 4);
        T[r][c4 * 4 + 0] = v.x; T[r][c4 * 4 + 1] = v.y;
        T[r][c4 * 4 + 2] = v.z; T[r][c4 * 4 + 3] = v.w;
    }
    __syncthreads();
#pragma unroll
    for (int i = 0; i < 4; ++i) {
        int c = tid + 256 * i; int r = c >> 4, c4 = c & 15;   // r = n_local, c4 = k group
        float x0 = T[c4 * 4 + 0][r], x1 = T[c4 * 4 + 1][r];
        float x2 = T[c4 * 4 + 2][r], x3 = T[c4 * 4 + 3][r];
        unsigned short h0 = f2bf(x0), h1 = f2bf(x1), h2 = f2bf(x2), h3 = f2bf(x3);
        unsigned short l0 = f2bf(x0 - bf2f(h0)), l1 = f2bf(x1 - bf2f(h1));
        unsigned short l2 = f2bf(x2 - bf2f(h2)), l3 = f2bf(x3 - bf2f(h3));
        size_t o = (size_t)w * 1048576 + (size_t)(n0 + r) * 1024 + k0 + c4 * 4;
        *(s4v*)&wt_hi[o] = (s4v){(short)h0, (short)h1, (short)h2, (short)h3};
        *(s4v*)&wt_lo[o] = (s4v){(short)l0, (short)l1, (short)l2, (short)l3};
    }
}

// ---------------------------------------------------------------------------
// Pack attn_mask int32 -> bitmask u64 words. One thread per word (64 ints).
// ---------------------------------------------------------------------------
__global__ __launch_bounds__(256)
void maskbits_kernel(const int* __restrict__ mask, unsigned long long* __restrict__ mb)
{
    const int w = blockIdx.x * 256 + threadIdx.x;   // 65536 words
    const int* p = mask + (size_t)w * 64;
    unsigned long long bits = 0;
#pragma unroll
    for (int i = 0; i < 16; ++i) {
        int4 v = *(const int4*)(p + i * 4);
        bits |= (unsigned long long)(v.x != 0) << (i * 4 + 0);
        bits |= (unsigned long long)(v.y != 0) << (i * 4 + 1);
        bits |= (unsigned long long)(v.z != 0) << (i * 4 + 2);
        bits |= (unsigned long long)(v.w != 0) << (i * 4 + 3);
    }
    mb[w] = bits;
}

// ---------------------------------------------------------------------------
// Split-bf16 MFMA GEMM body (projections / out-proj). Unchanged from round 2.
// ---------------------------------------------------------------------------
template<int ASRC, int EPI>
__device__ __forceinline__ void gemm_body(
    const float* __restrict__ Af,
    const unsigned short* __restrict__ Ah_g, const unsigned short* __restrict__ Al_g,
    const unsigned short* __restrict__ Bh_g, const unsigned short* __restrict__ Bl_g,
    const float* __restrict__ bias,
    float* __restrict__ Yf, unsigned short* __restrict__ Yh, unsigned short* __restrict__ Yl,
    unsigned short* As_h, unsigned short* As_l, unsigned short* Bs_h, unsigned short* Bs_l,
    int m0, int n0)
{
    const int tid = threadIdx.x, lane = tid & 63, wid = tid >> 6;
    const int wm = (wid >> 1) * 64, wn = (wid & 1) * 64;
    f32x4 zero4 = {0.f, 0.f, 0.f, 0.f};
    f32x4 acc[4][4];
#pragma unroll
    for (int a = 0; a < 4; ++a)
#pragma unroll
        for (int b = 0; b < 4; ++b) acc[a][b] = zero4;

    for (int kt = 0; kt < 1024; kt += 64) {
        __syncthreads();
        if (ASRC == 0) {
#pragma unroll
            for (int i = 0; i < 8; ++i) {
                int c = tid + 256 * i; int r = c >> 4, c4 = c & 15;
                f32x4 v = *(const f32x4*)(Af + (size_t)(m0 + r) * 1024 + kt + c4 * 4);
                unsigned short h0 = f2bf(v.x), h1 = f2bf(v.y), h2 = f2bf(v.z), h3 = f2bf(v.w);
                unsigned short l0 = f2bf(v.x - bf2f(h0)), l1 = f2bf(v.y - bf2f(h1));
                unsigned short l2 = f2bf(v.z - bf2f(h2)), l3 = f2bf(v.w - bf2f(h3));
                int off = r * 64 + (((c4 >> 1) ^ (r & 7)) * 8) + (c4 & 1) * 4;
                *(s4v*)&As_h[off] = (s4v){(short)h0, (short)h1, (short)h2, (short)h3};
                *(s4v*)&As_l[off] = (s4v){(short)l0, (short)l1, (short)l2, (short)l3};
            }
        } else {
#pragma unroll
            for (int i = 0; i < 4; ++i) {
                int c = tid + 256 * i; int r = c >> 3, cc = c & 7;
                int off = r * 64 + ((cc ^ (r & 7)) * 8);
                *(bf8*)&As_h[off] = *(const bf8*)(Ah_g + (size_t)(m0 + r) * 1024 + kt + cc * 8);
                *(bf8*)&As_l[off] = *(const bf8*)(Al_g + (size_t)(m0 + r) * 1024 + kt + cc * 8);
            }
        }
#pragma unroll
        for (int i = 0; i < 4; ++i) {
            int c = tid + 256 * i; int r = c >> 3, cc = c & 7;
            int off = r * 64 + ((cc ^ (r & 7)) * 8);
            *(bf8*)&Bs_h[off] = *(const bf8*)(Bh_g + (size_t)(n0 + r) * 1024 + kt + cc * 8);
            *(bf8*)&Bs_l[off] = *(const bf8*)(Bl_g + (size_t)(n0 + r) * 1024 + kt + cc * 8);
        }
        __syncthreads();
#pragma unroll
        for (int ks = 0; ks < 2; ++ks) {
            bf8 ah[4], al[4], bh[4], bl[4];
#pragma unroll
            for (int f = 0; f < 4; ++f) {
                int ra = wm + f * 16 + (lane & 15);
                int ca = (ks * 4 + (lane >> 4)) ^ (ra & 7);
                ah[f] = *(const bf8*)&As_h[ra * 64 + ca * 8];
                al[f] = *(const bf8*)&As_l[ra * 64 + ca * 8];
                int rb = wn + f * 16 + (lane & 15);
                int cb = (ks * 4 + (lane >> 4)) ^ (rb & 7);
                bh[f] = *(const bf8*)&Bs_h[rb * 64 + cb * 8];
                bl[f] = *(const bf8*)&Bs_l[rb * 64 + cb * 8];
            }
#pragma unroll
            for (int fi = 0; fi < 4; ++fi)
#pragma unroll
                for (int fj = 0; fj < 4; ++fj) {
                    acc[fi][fj] = MFMA(ah[fi], bh[fj], acc[fi][fj]);
                    acc[fi][fj] = MFMA(al[fi], bh[fj], acc[fi][fj]);
                    acc[fi][fj] = MFMA(ah[fi], bl[fj], acc[fi][fj]);
                }
        }
    }
    // epilogue: C/D layout (m89): col = lane&15, row = (lane>>4)*4 + reg
#pragma unroll
    for (int fi = 0; fi < 4; ++fi)
#pragma unroll
        for (int fj = 0; fj < 4; ++fj)
#pragma unroll
            for (int rg = 0; rg < 4; ++rg) {
                int m = m0 + wm + fi * 16 + ((lane >> 4) << 2) + rg;
                int n = n0 + wn + fj * 16 + (lane & 15);
                float val = acc[fi][fj][rg] + bias[n];
                if (EPI == 0) {
                    int b = m >> 10, s = m & 1023, h = n >> 6, d = n & 63;
                    size_t o = (((size_t)(b * 16 + h)) * 1024 + s) * 64 + d;
                    unsigned short hv = f2bf(val);
                    unsigned short lv = f2bf(val - bf2f(hv));
                    Yh[o] = hv; Yl[o] = lv;
                } else {
                    Yf[(size_t)m * 1024 + n] = val;
                }
            }
}

__global__ __launch_bounds__(256, 2)
void proj_qkv_kernel(const float* __restrict__ q_in, const float* __restrict__ k_in,
                     const float* __restrict__ v_in,
                     const unsigned short* __restrict__ wt_hi, const unsigned short* __restrict__ wt_lo,
                     const float* __restrict__ bq, const float* __restrict__ bk,
                     const float* __restrict__ bv,
                     unsigned short* qh_hi, unsigned short* qh_lo,
                     unsigned short* kh_hi, unsigned short* kh_lo,
                     unsigned short* vh_hi, unsigned short* vh_lo)
{
    __shared__ __align__(16) unsigned short As_h[128 * 64], As_l[128 * 64];
    __shared__ __align__(16) unsigned short Bs_h[128 * 64], Bs_l[128 * 64];
    const int z = blockIdx.z;
    const float* X = z == 0 ? q_in : (z == 1 ? k_in : v_in);
    const float* bias = z == 0 ? bq : (z == 1 ? bk : bv);
    unsigned short* Yh = z == 0 ? qh_hi : (z == 1 ? kh_hi : vh_hi);
    unsigned short* Yl = z == 0 ? qh_lo : (z == 1 ? kh_lo : vh_lo);
    gemm_body<0, 0>(X, nullptr, nullptr,
                    wt_hi + (size_t)z * 1048576, wt_lo + (size_t)z * 1048576,
                    bias, nullptr, Yh, Yl, As_h, As_l, Bs_h, Bs_l,
                    blockIdx.x * 128, blockIdx.y * 128);
}

__global__ __launch_bounds__(256, 2)
void outproj_kernel(const unsigned short* __restrict__ ctx_hi, const unsigned short* __restrict__ ctx_lo,
                    const unsigned short* __restrict__ wo_hi, const unsigned short* __restrict__ wo_lo,
                    const float* __restrict__ bo, float* __restrict__ out)
{
    __shared__ __align__(16) unsigned short As_h[128 * 64], As_l[128 * 64];
    __shared__ __align__(16) unsigned short Bs_h[128 * 64], Bs_l[128 * 64];
    gemm_body<1, 1>(nullptr, ctx_hi, ctx_lo, wo_hi, wo_lo, bo, out, nullptr, nullptr,
                    As_h, As_l, Bs_h, Bs_l, blockIdx.x * 128, blockIdx.y * 128);
}

// ---------------------------------------------------------------------------
// V transpose: vh[bh][s][d] (ushort) -> vt[bh][d][s]. z: 0=hi,1=lo buffers.
// ---------------------------------------------------------------------------
__global__ __launch_bounds__(256, 4)
void vtrans_kernel(const unsigned short* __restrict__ vh_hi, const unsigned short* __restrict__ vh_lo,
                   unsigned short* __restrict__ vt_hi, unsigned short* __restrict__ vt_lo)
{
    __shared__ unsigned short T[64][72];
    const unsigned short* src = blockIdx.z ? vh_lo : vh_hi;
    unsigned short* dst = blockIdx.z ? vt_lo : vt_hi;
    const int st = blockIdx.x * 64, bh = blockIdx.y, tid = threadIdx.x;
#pragma unroll
    for (int i = 0; i < 4; ++i) {
        int c = tid + 256 * i; int r = c >> 4, d4 = c & 15;
        s4v v = *(const s4v*)(src + ((size_t)bh * 1024 + st + r) * 64 + d4 * 4);
        T[r][d4 * 4 + 0] = (unsigned short)v.x; T[r][d4 * 4 + 1] = (unsigned short)v.y;
        T[r][d4 * 4 + 2] = (unsigned short)v.z; T[r][d4 * 4 + 3] = (unsigned short)v.w;
    }
    __syncthreads();
#pragma unroll
    for (int i = 0; i < 4; ++i) {
        int c = tid + 256 * i; int r = c >> 4, s4_ = c & 15;  // r = d row
        s4v o = {(short)T[s4_ * 4 + 0][r], (short)T[s4_ * 4 + 1][r],
                 (short)T[s4_ * 4 + 2][r], (short)T[s4_ * 4 + 3][r]};
        *(s4v*)(dst + ((size_t)bh * 64 + r) * 1024 + st + s4_ * 4) = o;
    }
}

// ---------------------------------------------------------------------------
// prel[row][r] = q_hi[row,:64] . emb[r,:64]  (row = bh*1024+s), bf16 out,
// global row stride PRELW=130.
// ---------------------------------------------------------------------------
__global__ __launch_bounds__(256, 2)
void relproj_kernel(const unsigned short* __restrict__ qh_hi, const float* __restrict__ emb,
                    unsigned short* __restrict__ prel)
{
    __shared__ float se[RR][68];
    __shared__ float sq[128][68];
    const int tid = threadIdx.x;
    const size_t row0 = (size_t)blockIdx.x * 128;
    for (int i = tid; i < RR * 64; i += 256) { int r = i >> 6, d = i & 63; se[r][d] = emb[i]; }
#pragma unroll
    for (int i = 0; i < 8; ++i) {
        int c = tid + 256 * i; int r = c >> 4, d4 = c & 15;
        s4v v = *(const s4v*)(qh_hi + (row0 + r) * 64 + d4 * 4);
        sq[r][d4 * 4 + 0] = bf2f((unsigned short)v.x);
        sq[r][d4 * 4 + 1] = bf2f((unsigned short)v.y);
        sq[r][d4 * 4 + 2] = bf2f((unsigned short)v.z);
        sq[r][d4 * 4 + 3] = bf2f((unsigned short)v.w);
    }
    __syncthreads();
    for (int idx = tid; idx < 128 * RR; idx += 256) {
        int r = idx / RR, c = idx - r * RR;
        const float* a = sq[r];
        const float* b = se[c];
        float s = 0.f;
#pragma unroll
        for (int d = 0; d < 64; ++d) s = fmaf(a[d], b[d], s);
        prel[(row0 + r) * PRELW + c] = f2bf(s);
    }
}

// ---------------------------------------------------------------------------
// Scores: swapped-operand MFMA (A=K rows -> C row=j, B=Q rows -> C col=i).
// Raw s = QK^T/8 + relbias (masked -1e30) written fp32 (float4 stores).
// Online row max/sum -> rowm/rowsum. prel in LDS; mask via bitmask; Q frags
// hoisted to registers.
// ---------------------------------------------------------------------------
__global__ __launch_bounds__(256, 2)
void scores_kernel(const unsigned short* __restrict__ qh_hi, const unsigned short* __restrict__ qh_lo,
                   const unsigned short* __restrict__ kh_hi, const unsigned short* __restrict__ kh_lo,
                   const unsigned short* __restrict__ prel, const unsigned long long* __restrict__ mb,
                   float* __restrict__ attn, float* __restrict__ rowm, float* __restrict__ rowsum)
{
    __shared__ __align__(16) unsigned short Sh[128 * 64], Sl[128 * 64];  // Q once, then K tiles
    __shared__ __align__(16) unsigned short Pr[128 * PRELW];
    __shared__ float Sm[2][128], Ss[2][128];
    const int tid = threadIdx.x, lane = tid & 63, wid = tid >> 6;
    const int wi = wid >> 1, wj = wid & 1;
    const int g = lane >> 4, li = lane & 15;
    const int i0 = blockIdx.x * 128, bh = blockIdx.y, b = bh >> 4;

    // stage Q tile (swizzled rows = i)
    const unsigned short* qbh = qh_hi + ((size_t)bh * 1024 + i0) * 64;
    const unsigned short* qbl = qh_lo + ((size_t)bh * 1024 + i0) * 64;
#pragma unroll
    for (int i = 0; i < 4; ++i) {
        int c = tid + 256 * i; int r = c >> 3, cc = c & 7;
        int off = r * 64 + ((cc ^ (r & 7)) * 8);
        *(bf8*)&Sh[off] = *(const bf8*)(qbh + r * 64 + cc * 8);
        *(bf8*)&Sl[off] = *(const bf8*)(qbl + r * 64 + cc * 8);
    }
    // stage prel rows: flat contiguous copy (128 rows x 65 u32)
    {
        const unsigned* src = (const unsigned*)(prel + ((size_t)bh * 1024 + i0) * PRELW);
        unsigned* dst = (unsigned*)Pr;
        for (int idx = tid; idx < 128 * (PRELW / 2); idx += 256) dst[idx] = src[idx];
    }
    __syncthreads();
    // Q fragments to registers (loop-invariant B operand)
    bf8 qfh[4][2], qfl[4][2];
#pragma unroll
    for (int fi = 0; fi < 4; ++fi)
#pragma unroll
        for (int ks = 0; ks < 2; ++ks) {
            int rb = wi * 64 + fi * 16 + li;
            int cb = (ks * 4 + g) ^ (rb & 7);
            qfh[fi][ks] = *(const bf8*)&Sh[rb * 64 + cb * 8];
            qfl[fi][ks] = *(const bf8*)&Sl[rb * 64 + cb * 8];
        }

    float rm[4], rs[4];
#pragma unroll
    for (int i = 0; i < 4; ++i) { rm[i] = -3.0e38f; rs[i] = 0.f; }

    for (int jt = 0; jt < 8; ++jt) {
        __syncthreads();   // guards Q-frag reads (jt=0) / prior-tile frag reads
        const unsigned short* kbh = kh_hi + ((size_t)bh * 1024 + jt * 128) * 64;
        const unsigned short* kbl = kh_lo + ((size_t)bh * 1024 + jt * 128) * 64;
#pragma unroll
        for (int i = 0; i < 4; ++i) {
            int c = tid + 256 * i; int r = c >> 3, cc = c & 7;
            int off = r * 64 + ((cc ^ (r & 7)) * 8);
            *(bf8*)&Sh[off] = *(const bf8*)(kbh + r * 64 + cc * 8);
            *(bf8*)&Sl[off] = *(const bf8*)(kbl + r * 64 + cc * 8);
        }
        __syncthreads();
        f32x4 zero4 = {0.f, 0.f, 0.f, 0.f};
        f32x4 acc[4][4];  // [fj][fi]
#pragma unroll
        for (int a = 0; a < 4; ++a)
#pragma unroll
            for (int c = 0; c < 4; ++c) acc[a][c] = zero4;
#pragma unroll
        for (int ks = 0; ks < 2; ++ks) {
            bf8 kfh[4], kfl[4];
#pragma unroll
            for (int fj = 0; fj < 4; ++fj) {
                int ra = wj * 64 + fj * 16 + li;
                int ca = (ks * 4 + g) ^ (ra & 7);
                kfh[fj] = *(const bf8*)&Sh[ra * 64 + ca * 8];
                kfl[fj] = *(const bf8*)&Sl[ra * 64 + ca * 8];
            }
#pragma unroll
            for (int fj = 0; fj < 4; ++fj)
#pragma unroll
                for (int fi = 0; fi < 4; ++fi) {
                    acc[fj][fi] = MFMA(kfh[fj], qfh[fi][ks], acc[fj][fi]);
                    acc[fj][fi] = MFMA(kfl[fj], qfh[fi][ks], acc[fj][fi]);
                    acc[fj][fi] = MFMA(kfh[fj], qfl[fi][ks], acc[fj][fi]);
                }
        }
        // epilogue: bias from LDS, mask from bitmask, float4 raw stores, stats
#pragma unroll
        for (int fi = 0; fi < 4; ++fi) {
            const int rowL = wi * 64 + fi * 16 + li;
            const int ii = i0 + rowL;
            const unsigned long long mw = mb[((size_t)b * 1024 + ii) * 16 + jt * 2 + wj];
            float p16[4][4];
            float tmax = -3.0e38f;
#pragma unroll
            for (int fj = 0; fj < 4; ++fj)
#pragma unroll
                for (int rg = 0; rg < 4; ++rg) {
                    int jloc = fj * 16 + g * 4 + rg;
                    int jj = jt * 128 + wj * 64 + jloc;
                    int dd = ii - jj; dd = dd < -64 ? -64 : (dd > 64 ? 64 : dd);
                    float s = acc[fj][fi][rg] * 0.125f + bf2f(Pr[rowL * PRELW + dd + 64]);
                    if (!((mw >> jloc) & 1ull)) s = -1.0e30f;
                    p16[fj][rg] = s;
                    tmax = fmaxf(tmax, s);
                }
            tmax = fmaxf(tmax, __shfl_xor(tmax, 16, 64));
            tmax = fmaxf(tmax, __shfl_xor(tmax, 32, 64));
            float nm = fmaxf(rm[fi], tmax);
            float ps = 0.f;
#pragma unroll
            for (int fj = 0; fj < 4; ++fj)
#pragma unroll
                for (int rg = 0; rg < 4; ++rg) ps += __expf(p16[fj][rg] - nm);
            ps += __shfl_xor(ps, 16, 64);
            ps += __shfl_xor(ps, 32, 64);
            rs[fi] = rs[fi] * __expf(rm[fi] - nm) + ps;
            rm[fi] = nm;
            float* arow = attn + ((size_t)bh * 1024 + ii) * 1024 + jt * 128 + wj * 64 + g * 4;
#pragma unroll
            for (int fj = 0; fj < 4; ++fj) {
                f32x4 st = {p16[fj][0], p16[fj][1], p16[fj][2], p16[fj][3]};
                *(f32x4*)(arow + fj * 16) = st;
            }
        }
    }
    // combine the two j-half waves per i-row
#pragma unroll
    for (int fi = 0; fi < 4; ++fi) {
        if (lane < 16) {
            Sm[wj][wi * 64 + fi * 16 + li] = rm[fi];
            Ss[wj][wi * 64 + fi * 16 + li] = rs[fi];
        }
    }
    __syncthreads();
    if (tid < 128) {
        float m0_ = Sm[0][tid], m1_ = Sm[1][tid];
        float mm = fmaxf(m0_, m1_);
        float ss = Ss[0][tid] * __expf(m0_ - mm) + Ss[1][tid] * __expf(m1_ - mm);
        rowm[(size_t)bh * 1024 + i0 + tid] = mm;
        rowsum[(size_t)bh * 1024 + i0 + tid] = ss;
    }
}

// ---------------------------------------------------------------------------
// PV: normalize raw scores in place (writes final attn weights), split to
// hi/lo bf16 in LDS, MFMA against transposed V. (Unchanged from round 2.)
// ---------------------------------------------------------------------------
__global__ __launch_bounds__(256, 2)
void pv_kernel(float* __restrict__ attn,
               const unsigned short* __restrict__ vt_hi, const unsigned short* __restrict__ vt_lo,
               const float* __restrict__ rowm, const float* __restrict__ rowsum,
               unsigned short* __restrict__ ctx_hi, unsigned short* __restrict__ ctx_lo)
{
    __shared__ __align__(16) unsigned short Ah[128 * 64], Al[128 * 64];
    __shared__ __align__(16) unsigned short Bh_[64 * 64], Bl_[64 * 64];
    const int tid = threadIdx.x, lane = tid & 63, wid = tid >> 6;
    const int i0 = blockIdx.x * 128, bh = blockIdx.y;

    float m8[8], inv8[8];
#pragma unroll
    for (int i = 0; i < 8; ++i) {
        int r = (tid >> 4) + 16 * i;
        m8[i] = rowm[(size_t)bh * 1024 + i0 + r];
        inv8[i] = 1.f / rowsum[(size_t)bh * 1024 + i0 + r];
    }
    f32x4 zero4 = {0.f, 0.f, 0.f, 0.f};
    f32x4 acc[2][4];
#pragma unroll
    for (int a = 0; a < 2; ++a)
#pragma unroll
        for (int c = 0; c < 4; ++c) acc[a][c] = zero4;

    for (int jt = 0; jt < 16; ++jt) {
        __syncthreads();
#pragma unroll
        for (int i = 0; i < 8; ++i) {
            int c = tid + 256 * i; int r = c >> 4, c4 = c & 15;
            size_t gidx = ((size_t)bh * 1024 + i0 + r) * 1024 + jt * 64 + c4 * 4;
            f32x4 v = *(f32x4*)(attn + gidx);
            float mm = m8[i], iv = inv8[i];
            v.x = __expf(v.x - mm) * iv; v.y = __expf(v.y - mm) * iv;
            v.z = __expf(v.z - mm) * iv; v.w = __expf(v.w - mm) * iv;
            *(f32x4*)(attn + gidx) = v;   // final attention weights
            unsigned short h0 = f2bf(v.x), h1 = f2bf(v.y), h2 = f2bf(v.z), h3 = f2bf(v.w);
            unsigned short l0 = f2bf(v.x - bf2f(h0)), l1 = f2bf(v.y - bf2f(h1));
            unsigned short l2 = f2bf(v.z - bf2f(h2)), l3 = f2bf(v.w - bf2f(h3));
            int off = r * 64 + (((c4 >> 1) ^ (r & 7)) * 8) + (c4 & 1) * 4;
            *(s4v*)&Ah[off] = (s4v){(short)h0, (short)h1, (short)h2, (short)h3};
            *(s4v*)&Al[off] = (s4v){(short)l0, (short)l1, (short)l2, (short)l3};
        }
#pragma unroll
        for (int i = 0; i < 2; ++i) {
            int c = tid + 256 * i; int r = c >> 3, cc = c & 7;
            int off = r * 64 + ((cc ^ (r & 7)) * 8);
            *(bf8*)&Bh_[off] = *(const bf8*)(vt_hi + ((size_t)bh * 64 + r) * 1024 + jt * 64 + cc * 8);
            *(bf8*)&Bl_[off] = *(const bf8*)(vt_lo + ((size_t)bh * 64 + r) * 1024 + jt * 64 + cc * 8);
        }
        __syncthreads();
#pragma unroll
        for (int ks = 0; ks < 2; ++ks) {
            bf8 ah[2], al[2], bhf[4], blf[4];
#pragma unroll
            for (int f = 0; f < 2; ++f) {
                int ra = wid * 32 + f * 16 + (lane & 15);
                int ca = (ks * 4 + (lane >> 4)) ^ (ra & 7);
                ah[f] = *(const bf8*)&Ah[ra * 64 + ca * 8];
                al[f] = *(const bf8*)&Al[ra * 64 + ca * 8];
            }
#pragma unroll
            for (int f = 0; f < 4; ++f) {
                int rb = f * 16 + (lane & 15);
                int cb = (ks * 4 + (lane >> 4)) ^ (rb & 7);
                bhf[f] = *(const bf8*)&Bh_[rb * 64 + cb * 8];
                blf[f] = *(const bf8*)&Bl_[rb * 64 + cb * 8];
            }
#pragma unroll
            for (int fi = 0; fi < 2; ++fi)
#pragma unroll
                for (int fj = 0; fj < 4; ++fj) {
                    acc[fi][fj] = MFMA(ah[fi], bhf[fj], acc[fi][fj]);
                    acc[fi][fj] = MFMA(al[fi], bhf[fj], acc[fi][fj]);
                    acc[fi][fj] = MFMA(ah[fi], blf[fj], acc[fi][fj]);
                }
        }
    }
    const int b = bh >> 4, h = bh & 15;
#pragma unroll
    for (int fi = 0; fi < 2; ++fi)
#pragma unroll
        for (int fj = 0; fj < 4; ++fj)
#pragma unroll
            for (int rg = 0; rg < 4; ++rg) {
                int ii = i0 + wid * 32 + fi * 16 + ((lane >> 4) << 2) + rg;
                int d = fj * 16 + (lane & 15);
                float val = acc[fi][fj][rg];
                size_t o = ((size_t)b * 1024 + ii) * 1024 + h * 64 + d;
                unsigned short hv = f2bf(val);
                unsigned short lv = f2bf(val - bf2f(hv));
                ctx_hi[o] = hv; ctx_lo[o] = lv;
            }
}

extern "C" void kernel_launch(void* const* d_in, const int* in_sizes, int n_in,
                              void* d_out, int out_size, void* d_ws, size_t ws_size,
                              hipStream_t stream)
{
    const float* query = (const float*)d_in[0];
    const float* key_  = (const float*)d_in[1];
    const float* value = (const float*)d_in[2];
    const int*   mask  = (const int*)d_in[3];
    const float* Wq = (const float*)d_in[4];
    const float* bq = (const float*)d_in[5];
    const float* Wk = (const float*)d_in[6];
    const float* bk = (const float*)d_in[7];
    const float* Wv = (const float*)d_in[8];
    const float* bv = (const float*)d_in[9];
    const float* Wo = (const float*)d_in[10];
    const float* bo = (const float*)d_in[11];
    const float* emb = (const float*)d_in[12];

    // workspace (exactly 84,148,224 B = round-1 proven footprint)
    unsigned short* wt_hi = (unsigned short*)d_ws;           // [4][1024][1024]
    unsigned short* wt_lo = wt_hi + (size_t)4 * 1048576;
    unsigned short* qh_hi = wt_lo + (size_t)4 * 1048576;     // [64][1024][64]
    unsigned short* qh_lo = qh_hi + 4194304;
    unsigned short* kh_hi = qh_lo + 4194304;
    unsigned short* kh_lo = kh_hi + 4194304;
    unsigned short* vt_hi = kh_lo + 4194304;                 // [64][64][1024]
    unsigned short* vt_lo = vt_hi + 4194304;
    unsigned short* prel  = vt_lo + 4194304;                 // [65536][130] bf16
    // stats + bitmask overlay the (dead-after-projection) Wq^T-hi region:
    float* rowm   = (float*)d_ws;                            // [65536]
    float* rowsum = rowm + 65536;
    unsigned long long* mb = (unsigned long long*)(rowsum + 65536);  // [65536]
    // ctx reuses q-heads (dead after scores/relproj):
    unsigned short* ctx_hi = qh_hi;
    unsigned short* ctx_lo = qh_lo;
    // v-heads scratch lives in the out region (written last):
    unsigned short* vh_hi = (unsigned short*)d_out;          // 16 MB region
    unsigned short* vh_lo = vh_hi + 4194304;

    float* out  = (float*)d_out;
    float* attn = (float*)d_out + 4194304;

    dim3 blk(256);
    wtrans_kernel<<<dim3(16, 16, 4), blk, 0, stream>>>(Wq, Wk, Wv, Wo, wt_hi, wt_lo);
    proj_qkv_kernel<<<dim3(32, 8, 3), blk, 0, stream>>>(query, key_, value, wt_hi, wt_lo,
                                                        bq, bk, bv, qh_hi, qh_lo,
                                                        kh_hi, kh_lo, vh_hi, vh_lo);
    maskbits_kernel<<<dim3(256), blk, 0, stream>>>(mask, mb);   // after proj (mb overlays Wq^T)
    vtrans_kernel<<<dim3(16, 64, 2), blk, 0, stream>>>(vh_hi, vh_lo, vt_hi, vt_lo);
    relproj_kernel<<<dim3(512), blk, 0, stream>>>(qh_hi, emb, prel);
    scores_kernel<<<dim3(8, 64), blk, 0, stream>>>(qh_hi, qh_lo, kh_hi, kh_lo, prel, mb,
                                                   attn, rowm, rowsum);
    pv_kernel<<<dim3(8, 64), blk, 0, stream>>>(attn, vt_hi, vt_lo, rowm, rowsum, ctx_hi, ctx_lo);
    outproj_kernel<<<dim3(32, 8), blk, 0, stream>>>(ctx_hi, ctx_lo,
                                                    wt_hi + (size_t)3 * 1048576,
                                                    wt_lo + (size_t)3 * 1048576, bo, out);
}